// Round 1
// baseline (4116.624 us; speedup 1.0000x reference)
//
#include <hip/hip_runtime.h>
#include <hip/hip_bf16.h>
#include <stdint.h>

#define N_B   64
#define C_IN  64
#define H_IMG 64
#define W_IMG 128
#define HW    8192
#define NH    8
#define C_QK  256
#define C_V   128
#define D_OUT 64

__device__ __forceinline__ float b2f(unsigned short u) {
    union { unsigned int i; float f; } x; x.i = ((unsigned int)u) << 16; return x.f;
}
__device__ __forceinline__ unsigned short f2b(float f) {
    union { float f; unsigned int i; } x; x.f = f;
    unsigned int lsb = (x.i >> 16) & 1u;
    x.i += 0x7fffu + lsb;
    return (unsigned short)(x.i >> 16);
}

// ---------------------------------------------------------------------------
// Conv: 3x3, pad 1. Block = (n, 64-channel block, 16x16 spatial tile).
// 384 total out channels: [0,256) -> qk_buf (from W_qk), [256,384) -> v_buf.
// fp32 accumulate, bf16 store.
// ---------------------------------------------------------------------------
__launch_bounds__(256)
__global__ void conv_kernel(const float* __restrict__ x,
                            const float* __restrict__ Wqk, const float* __restrict__ bqk,
                            const float* __restrict__ Wv,  const float* __restrict__ bv,
                            unsigned short* __restrict__ qk_buf,
                            unsigned short* __restrict__ v_buf)
{
    __shared__ float x_s[16 * 18 * 18];   // [ci][r][c], 18x18 halo tile
    __shared__ float w_s[64 * 144];       // [co][ci*9 + tap]

    const int t    = threadIdx.x;
    const int tile = blockIdx.x;          // 0..31  (4 x 8 tiles of 16x16)
    const int cb   = blockIdx.y;          // 0..5   (64-channel blocks of 384)
    const int n    = blockIdx.z;          // 0..63
    const int ti = tile >> 3, tj = tile & 7;
    const int i0 = ti * 16, j0 = tj * 16;
    const int tx  = t & 31;               // pixel group
    const int co0 = (t >> 5) * 8;         // 8 channels per thread

    const bool is_v = (cb >= 4);
    const float* Wsrc  = is_v ? Wv : Wqk;
    const int co_base  = is_v ? (cb - 4) * 64 : cb * 64;  // within its own tensor

    float acc[8][8];
    #pragma unroll
    for (int i = 0; i < 8; ++i)
        #pragma unroll
        for (int p = 0; p < 8; ++p) acc[i][p] = 0.f;

    for (int cc = 0; cc < 4; ++cc) {      // 16-input-channel chunks
        __syncthreads();
        // stage x tile (16ci x 18 x 18), zero-padded
        for (int idx = t; idx < 16 * 324; idx += 256) {
            int ci  = idx / 324;
            int rem = idx - ci * 324;
            int r   = rem / 18;
            int c   = rem - r * 18;
            int gi = i0 - 1 + r, gj = j0 - 1 + c;
            float v = 0.f;
            if ((unsigned)gi < (unsigned)H_IMG && (unsigned)gj < (unsigned)W_IMG)
                v = x[((size_t)(n * C_IN + cc * 16 + ci)) * HW + gi * W_IMG + gj];
            x_s[idx] = v;
        }
        // stage weights (64co x 16ci x 9)
        for (int idx = t; idx < 64 * 144; idx += 256) {
            int co = idx / 144;
            int r  = idx - co * 144;
            w_s[idx] = Wsrc[(size_t)(co_base + co) * 576 + cc * 144 + r];
        }
        __syncthreads();

        for (int ci = 0; ci < 16; ++ci) {
            #pragma unroll
            for (int di = 0; di < 3; ++di)
                #pragma unroll
                for (int dj = 0; dj < 3; ++dj) {
                    float wr[8];
                    #pragma unroll
                    for (int i = 0; i < 8; ++i)
                        wr[i] = w_s[(co0 + i) * 144 + ci * 9 + di * 3 + dj];
                    #pragma unroll
                    for (int p = 0; p < 8; ++p) {
                        int pix = tx + 32 * p;
                        int r = pix >> 4, c = pix & 15;
                        float xv = x_s[ci * 324 + (r + di) * 18 + (c + dj)];
                        #pragma unroll
                        for (int i = 0; i < 8; ++i)
                            acc[i][p] = fmaf(xv, wr[i], acc[i][p]);
                    }
                }
        }
    }

    // store bf16
    #pragma unroll
    for (int i = 0; i < 8; ++i) {
        int cog = cb * 64 + co0 + i;      // global channel among 384
        unsigned short* dst;
        size_t chan_base;
        float bias;
        if (cog < 256) { dst = qk_buf; chan_base = (size_t)(n * 256 + cog) * HW; bias = bqk[cog]; }
        else           { dst = v_buf;  chan_base = (size_t)(n * 128 + (cog - 256)) * HW; bias = bv[cog - 256]; }
        #pragma unroll
        for (int p = 0; p < 8; ++p) {
            int pix = tx + 32 * p;
            int r = pix >> 4, c = pix & 15;
            dst[chan_base + (size_t)(i0 + r) * W_IMG + (j0 + c)] = f2b(acc[i][p] + bias);
        }
    }
}

// ---------------------------------------------------------------------------
// A[h][n][m] = sum_{c,pix} q[n,h,c,pix] * k[m,h,c,pix]   (unscaled; atomicAdd)
// Block = (256-pixel chunk, head). q ch = h*32+c, k ch = h*32+16+c.
// ---------------------------------------------------------------------------
__launch_bounds__(256)
__global__ void a_kernel(const unsigned short* __restrict__ qk_buf,
                         float* __restrict__ A)
{
    __shared__ float q_s[64][129];
    __shared__ float k_s[64][129];
    const int t     = threadIdx.x;
    const int chunk = blockIdx.x;     // 0..31
    const int h     = blockIdx.y;     // 0..7
    const int p0    = chunk * 256;
    const int m0 = (t & 15) * 4;
    const int n0 = (t >> 4) * 4;

    float acc[4][4];
    #pragma unroll
    for (int i = 0; i < 4; ++i)
        #pragma unroll
        for (int j = 0; j < 4; ++j) acc[i][j] = 0.f;

    for (int sub = 0; sub < 32; ++sub) {
        const int ps = p0 + sub * 8;
        __syncthreads();
        for (int v8 = t; v8 < 1024; v8 += 256) {   // 64n x 16c, 8 pixels each
            int nn = v8 >> 4, c = v8 & 15;
            const unsigned short* qp = qk_buf + (size_t)(nn * 256 + h * 32 + c) * HW + ps;
            const unsigned short* kp = qk_buf + (size_t)(nn * 256 + h * 32 + 16 + c) * HW + ps;
            uint4 qv = *reinterpret_cast<const uint4*>(qp);
            uint4 kv = *reinterpret_cast<const uint4*>(kp);
            const unsigned short* qu = reinterpret_cast<const unsigned short*>(&qv);
            const unsigned short* ku = reinterpret_cast<const unsigned short*>(&kv);
            #pragma unroll
            for (int j = 0; j < 8; ++j) q_s[nn][c * 8 + j] = b2f(qu[j]);
            #pragma unroll
            for (int j = 0; j < 8; ++j) k_s[nn][c * 8 + j] = b2f(ku[j]);
        }
        __syncthreads();
        #pragma unroll 4
        for (int r = 0; r < 128; ++r) {
            float qr[4], kr[4];
            #pragma unroll
            for (int i = 0; i < 4; ++i) qr[i] = q_s[n0 + i][r];
            #pragma unroll
            for (int j = 0; j < 4; ++j) kr[j] = k_s[m0 + j][r];
            #pragma unroll
            for (int i = 0; i < 4; ++i)
                #pragma unroll
                for (int j = 0; j < 4; ++j)
                    acc[i][j] = fmaf(qr[i], kr[j], acc[i][j]);
        }
    }
    #pragma unroll
    for (int i = 0; i < 4; ++i)
        #pragma unroll
        for (int j = 0; j < 4; ++j)
            atomicAdd(&A[(h * 64 + n0 + i) * 64 + m0 + j], acc[i][j]);
}

// ---------------------------------------------------------------------------
// softmax over m, with 1/sqrt(D_K*H*W) scaling folded in. One wave per row.
// ---------------------------------------------------------------------------
__global__ void softmax_kernel(const float* __restrict__ A, float* __restrict__ softA)
{
    const int row  = blockIdx.x;       // 0..511  (h*64+n)
    const int lane = threadIdx.x;      // 0..63
    const float inv_scale = (float)(1.0 / 362.03867196751236); // 1/sqrt(131072)
    float v = A[row * 64 + lane] * inv_scale;
    float mx = v;
    #pragma unroll
    for (int o = 32; o > 0; o >>= 1) mx = fmaxf(mx, __shfl_xor(mx, o, 64));
    float e = expf(v - mx);
    float s = e;
    #pragma unroll
    for (int o = 32; o > 0; o >>= 1) s += __shfl_xor(s, o, 64);
    softA[row * 64 + lane] = e / s;
}

// ---------------------------------------------------------------------------
// sa[n][k][pix] = sum_m softA[h(k)][n][m] * v[m][k][pix]; bf16 out.
// Block = (k, 128-pixel chunk).
// ---------------------------------------------------------------------------
__launch_bounds__(256)
__global__ void sa_kernel(const unsigned short* __restrict__ v_buf,
                          const float* __restrict__ softA,
                          unsigned short* __restrict__ sa_buf)
{
    __shared__ float sA[64 * 64];
    __shared__ float v_s[64 * 128];
    const int t = threadIdx.x;
    const int b = blockIdx.x;
    const int k     = b >> 6;      // 0..127
    const int chunk = b & 63;
    const int p0 = chunk * 128;
    const int h  = k >> 4;

    for (int idx = t; idx < 4096; idx += 256) sA[idx] = softA[h * 4096 + idx];
    for (int v8 = t; v8 < 1024; v8 += 256) {
        int m = v8 >> 4, pp = v8 & 15;
        uint4 vv = *reinterpret_cast<const uint4*>(v_buf + (size_t)(m * 128 + k) * HW + p0 + pp * 8);
        const unsigned short* u = reinterpret_cast<const unsigned short*>(&vv);
        #pragma unroll
        for (int j = 0; j < 8; ++j) v_s[m * 128 + pp * 8 + j] = b2f(u[j]);
    }
    __syncthreads();

    const int p  = t & 63;
    const int n0 = (t >> 6) * 16;
    float acc[16][2];
    #pragma unroll
    for (int i = 0; i < 16; ++i) { acc[i][0] = 0.f; acc[i][1] = 0.f; }
    for (int m = 0; m < 64; ++m) {
        float v0 = v_s[m * 128 + p];
        float v1 = v_s[m * 128 + p + 64];
        #pragma unroll
        for (int i = 0; i < 16; ++i) {
            float a = sA[(n0 + i) * 64 + m];
            acc[i][0] = fmaf(a, v0, acc[i][0]);
            acc[i][1] = fmaf(a, v1, acc[i][1]);
        }
    }
    #pragma unroll
    for (int i = 0; i < 16; ++i) {
        size_t base = (size_t)((n0 + i) * 128 + k) * HW + p0;
        sa_buf[base + p]      = f2b(acc[i][0]);
        sa_buf[base + p + 64] = f2b(acc[i][1]);
    }
}

// ---------------------------------------------------------------------------
// out[n][d][pix] = sum_k sa[n][k][pix] * Wout[k][d] + bout[d]; fp32 out.
// Block = (n, 128-pixel chunk).
// ---------------------------------------------------------------------------
__launch_bounds__(256)
__global__ void out_kernel(const unsigned short* __restrict__ sa_buf,
                           const float* __restrict__ Wout,
                           const float* __restrict__ bout,
                           float* __restrict__ out)
{
    __shared__ __align__(16) unsigned short sa_s[128 * 128];
    __shared__ float w_s[128 * 64];
    const int t = threadIdx.x;
    const int b = blockIdx.x;
    const int n     = b >> 6;
    const int chunk = b & 63;
    const int p0 = chunk * 128;

    for (int idx = t; idx < 8192; idx += 256) w_s[idx] = Wout[idx];
    for (int v8 = t; v8 < 2048; v8 += 256) {
        int k = v8 >> 4, pp = v8 & 15;
        uint4 vv = *reinterpret_cast<const uint4*>(sa_buf + (size_t)(n * 128 + k) * HW + p0 + pp * 8);
        *reinterpret_cast<uint4*>(&sa_s[k * 128 + pp * 8]) = vv;
    }
    __syncthreads();

    const int p  = t & 63;
    const int d0 = (t >> 6) * 16;
    float acc[16][2];
    #pragma unroll
    for (int i = 0; i < 16; ++i) { acc[i][0] = 0.f; acc[i][1] = 0.f; }
    for (int k = 0; k < 128; ++k) {
        float s0 = b2f(sa_s[k * 128 + p]);
        float s1 = b2f(sa_s[k * 128 + p + 64]);
        #pragma unroll
        for (int i = 0; i < 16; ++i) {
            float w = w_s[k * 64 + d0 + i];
            acc[i][0] = fmaf(s0, w, acc[i][0]);
            acc[i][1] = fmaf(s1, w, acc[i][1]);
        }
    }
    #pragma unroll
    for (int i = 0; i < 16; ++i) {
        float bb = bout[d0 + i];
        size_t base = (size_t)(n * 64 + d0 + i) * HW + p0;
        out[base + p]      = acc[i][0] + bb;
        out[base + p + 64] = acc[i][1] + bb;
    }
}

// ---------------------------------------------------------------------------
extern "C" void kernel_launch(void* const* d_in, const int* in_sizes, int n_in,
                              void* d_out, int out_size, void* d_ws, size_t ws_size,
                              hipStream_t stream)
{
    const float* x    = (const float*)d_in[0];
    const float* Wqk  = (const float*)d_in[1];
    const float* bqk  = (const float*)d_in[2];
    const float* Wv   = (const float*)d_in[3];
    const float* bv   = (const float*)d_in[4];
    const float* Wout = (const float*)d_in[5];
    const float* bout = (const float*)d_in[6];
    float* out = (float*)d_out;

    char* ws = (char*)d_ws;
    // layout: qk_buf bf16 [64][256][8192] (268435456 B)  -- reused as sa_buf
    //         v_buf  bf16 [64][128][8192] (134217728 B)
    //         A      f32  [8][64][64]     (131072 B)
    //         softA  f32  [8][64][64]     (131072 B)
    unsigned short* qk_buf = (unsigned short*)ws;
    unsigned short* v_buf  = (unsigned short*)(ws + 268435456u);
    float* A     = (float*)(ws + 268435456u + 134217728u);
    float* softA = (float*)(ws + 268435456u + 134217728u + 131072u);
    unsigned short* sa_buf = qk_buf;   // overlays dead q/k after A computed

    hipMemsetAsync(A, 0, 131072, stream);
    conv_kernel<<<dim3(32, 6, 64), 256, 0, stream>>>(x, Wqk, bqk, Wv, bv, qk_buf, v_buf);
    a_kernel<<<dim3(32, 8), 256, 0, stream>>>(qk_buf, A);
    softmax_kernel<<<512, 64, 0, stream>>>(A, softA);
    sa_kernel<<<8192, 256, 0, stream>>>(v_buf, softA, sa_buf);
    out_kernel<<<4096, 256, 0, stream>>>(sa_buf, Wout, bout, out);
}

// Round 2
// 1399.308 us; speedup vs baseline: 2.9419x; 2.9419x over previous
//
#include <hip/hip_runtime.h>
#include <hip/hip_bf16.h>
#include <stdint.h>

#define HW    8192
typedef unsigned short ushort_t;
typedef short short8 __attribute__((ext_vector_type(8)));
typedef float f32x4 __attribute__((ext_vector_type(4)));

__device__ __forceinline__ float b2f(unsigned short u) {
    union { unsigned int i; float f; } x; x.i = ((unsigned int)u) << 16; return x.f;
}
__device__ __forceinline__ unsigned short f2b(float f) {
    union { float f; unsigned int i; } x; x.f = f;
    unsigned int lsb = (x.i >> 16) & 1u;
    x.i += 0x7fffu + lsb;
    return (unsigned short)(x.i >> 16);
}

// ---------------------------------------------------------------------------
// Pre-cast weights to bf16, layout Wb[tap][co][ci]  (tap=di*3+dj, co 0..383)
// co < 256 from W_qk, co >= 256 from W_v.  W global layout: [co][ci][di][dj].
// ---------------------------------------------------------------------------
__global__ void cast_w_kernel(const float* __restrict__ Wqk,
                              const float* __restrict__ Wv,
                              unsigned short* __restrict__ Wb)
{
    const int co = blockIdx.x;            // 0..383
    const int t  = threadIdx.x;
    const float* src = (co < 256) ? (Wqk + (size_t)co * 576)
                                  : (Wv + (size_t)(co - 256) * 576);
    for (int idx = t; idx < 576; idx += 256) {
        const int ci  = idx / 9;
        const int tap = idx - ci * 9;
        Wb[(size_t)tap * (384 * 64) + co * 64 + ci] = f2b(src[idx]);
    }
}

// ---------------------------------------------------------------------------
// Implicit-GEMM conv via MFMA.  Block: 512 thr (8 waves), 128co x 256pix tile.
// K = 64ci*9tap, stepped as (tap, ci-chunk of 32).  x halo tile staged once
// (bf16, XOR-swizzled 16B granules); W double-buffered per K-step.
// ---------------------------------------------------------------------------
__launch_bounds__(512, 4)
__global__ void conv_mfma_kernel(const float* __restrict__ x,
                                 const unsigned short* __restrict__ Wb,
                                 const float* __restrict__ bqk,
                                 const float* __restrict__ bv,
                                 unsigned short* __restrict__ qk_buf,
                                 unsigned short* __restrict__ v_buf)
{
    __shared__ __align__(16) unsigned short x_s[324 * 64];   // [pos 0..323][64ci], swizzled
    __shared__ __align__(16) unsigned short w_s[2][128 * 32]; // [buf][co][32k], swizzled

    const int t   = threadIdx.x;
    const int cb  = blockIdx.x;           // 0..2   (co0 = cb*128)
    const int pb  = blockIdx.y;           // 0..31  (16x16 pixel tiles)
    const int n   = blockIdx.z;           // 0..63
    const int co0 = cb * 128;
    const int i0  = (pb >> 3) * 16;
    const int j0  = (pb & 7) * 16;
    const bool is_v = (cb == 2);

    // ---- stage x halo tile: 18 rows x 18 cols x 64 ci, fp32 -> bf16 ----
    for (int task = t; task < 18 * 64; task += 512) {
        const int rr = task >> 6;         // 0..17
        const int ci = task & 63;
        const int gi = i0 - 1 + rr;
        const bool row_ok = ((unsigned)gi < 64u);
        const float* xrow = x + (size_t)(n * 64 + ci) * HW + gi * 128;
        const int g_hi = ci >> 3, c_lo = ci & 7;
        #pragma unroll
        for (int cc = 0; cc < 18; ++cc) {
            const int gj = j0 - 1 + cc;
            float v = 0.f;
            if (row_ok && (unsigned)gj < 128u) v = xrow[gj];
            const int pos = rr * 18 + cc;
            x_s[pos * 64 + (((g_hi ^ (pos & 7)) << 3) | c_lo)] = f2b(v);
        }
    }

    // ---- staging roles for W (one uint4 = 8 bf16 per thread per step) ----
    const int wco = t >> 2;               // 0..127
    const int wkg = t & 3;                // k-granule 0..3
    const int wdst = wco * 32 + ((wkg ^ ((wco >> 1) & 3)) << 3);

    // stage step 0 (tap 0, cic 0)
    {
        const uint4 v = *reinterpret_cast<const uint4*>(
            Wb + (size_t)(co0 + wco) * 64 + wkg * 8);
        *reinterpret_cast<uint4*>(&w_s[0][wdst]) = v;
    }
    __syncthreads();

    // ---- wave decomposition: 8 waves = 2 co-halves x 4 pixel-row-quads ----
    const int lane15 = t & 15;
    const int lg     = (t >> 4) & 3;
    const int wid    = t >> 6;            // 0..7
    const int wco0   = (wid >> 2) * 64;   // 0 or 64
    const int pq     = wid & 3;           // pixel row quad (rows pq*4..pq*4+3)

    int aoff[4];
    #pragma unroll
    for (int m = 0; m < 4; ++m) {
        const int co_l = wco0 + m * 16 + lane15;
        aoff[m] = co_l * 32 + ((lg ^ ((co_l >> 1) & 3)) << 3);
    }

    f32x4 acc[4][4];
    #pragma unroll
    for (int m = 0; m < 4; ++m)
        #pragma unroll
        for (int r = 0; r < 4; ++r)
            acc[m][r] = (f32x4){0.f, 0.f, 0.f, 0.f};

    for (int s = 0; s < 18; ++s) {
        const int buf = s & 1;
        const int tap = s >> 1;
        const int cic = s & 1;

        // prefetch next K-step's W into regs (latency hides under MFMA)
        uint4 wpre;
        if (s < 17) {
            const int s2 = s + 1;
            const int tap2 = s2 >> 1, cic2 = s2 & 1;
            wpre = *reinterpret_cast<const uint4*>(
                Wb + (size_t)tap2 * (384 * 64) + (size_t)(co0 + wco) * 64 + cic2 * 32 + wkg * 8);
        }

        const int di = tap / 3;
        const int dj = tap - di * 3;

        short8 afrag[4];
        const unsigned short* wbase = &w_s[buf][0];
        #pragma unroll
        for (int m = 0; m < 4; ++m)
            afrag[m] = *reinterpret_cast<const short8*>(wbase + aoff[m]);

        #pragma unroll
        for (int r = 0; r < 4; ++r) {
            const int pos = (pq * 4 + r + di) * 18 + (lane15 + dj);
            const short8 bfrag = *reinterpret_cast<const short8*>(
                &x_s[pos * 64 + (((cic * 4 + lg) ^ (pos & 7)) << 3)]);
            #pragma unroll
            for (int m = 0; m < 4; ++m)
                acc[m][r] = __builtin_amdgcn_mfma_f32_16x16x32_bf16(
                    afrag[m], bfrag, acc[m][r], 0, 0, 0);
        }

        if (s < 17)
            *reinterpret_cast<uint4*>(&w_s[buf ^ 1][wdst]) = wpre;
        __syncthreads();
    }

    // ---- epilogue: bias + bf16 store.  C/D: col=lane15 (pixel), row=4*lg+reg (co)
    #pragma unroll
    for (int m = 0; m < 4; ++m) {
        #pragma unroll
        for (int reg = 0; reg < 4; ++reg) {
            const int cog = co0 + wco0 + m * 16 + lg * 4 + reg;
            const float bias = is_v ? bv[cog - 256] : bqk[cog];
            unsigned short* dst = is_v
                ? (v_buf  + (size_t)(n * 128 + (cog - 256)) * HW)
                : (qk_buf + (size_t)(n * 256 + cog) * HW);
            #pragma unroll
            for (int r = 0; r < 4; ++r) {
                const int pr = pq * 4 + r;
                dst[(size_t)(i0 + pr) * 128 + j0 + lane15] = f2b(acc[m][r][reg] + bias);
            }
        }
    }
}

// ---------------------------------------------------------------------------
// A[h][n][m] = sum_{c,pix} q[n,h,c,pix] * k[m,h,c,pix]   (unscaled; atomicAdd)
// ---------------------------------------------------------------------------
__launch_bounds__(256)
__global__ void a_kernel(const unsigned short* __restrict__ qk_buf,
                         float* __restrict__ A)
{
    __shared__ float q_s[64][129];
    __shared__ float k_s[64][129];
    const int t     = threadIdx.x;
    const int chunk = blockIdx.x;     // 0..31
    const int h     = blockIdx.y;     // 0..7
    const int p0    = chunk * 256;
    const int m0 = (t & 15) * 4;
    const int n0 = (t >> 4) * 4;

    float acc[4][4];
    #pragma unroll
    for (int i = 0; i < 4; ++i)
        #pragma unroll
        for (int j = 0; j < 4; ++j) acc[i][j] = 0.f;

    for (int sub = 0; sub < 32; ++sub) {
        const int ps = p0 + sub * 8;
        __syncthreads();
        for (int v8 = t; v8 < 1024; v8 += 256) {
            int nn = v8 >> 4, c = v8 & 15;
            const unsigned short* qp = qk_buf + (size_t)(nn * 256 + h * 32 + c) * HW + ps;
            const unsigned short* kp = qk_buf + (size_t)(nn * 256 + h * 32 + 16 + c) * HW + ps;
            uint4 qv = *reinterpret_cast<const uint4*>(qp);
            uint4 kv = *reinterpret_cast<const uint4*>(kp);
            const unsigned short* qu = reinterpret_cast<const unsigned short*>(&qv);
            const unsigned short* ku = reinterpret_cast<const unsigned short*>(&kv);
            #pragma unroll
            for (int j = 0; j < 8; ++j) q_s[nn][c * 8 + j] = b2f(qu[j]);
            #pragma unroll
            for (int j = 0; j < 8; ++j) k_s[nn][c * 8 + j] = b2f(ku[j]);
        }
        __syncthreads();
        #pragma unroll 4
        for (int r = 0; r < 128; ++r) {
            float qr[4], kr[4];
            #pragma unroll
            for (int i = 0; i < 4; ++i) qr[i] = q_s[n0 + i][r];
            #pragma unroll
            for (int j = 0; j < 4; ++j) kr[j] = k_s[m0 + j][r];
            #pragma unroll
            for (int i = 0; i < 4; ++i)
                #pragma unroll
                for (int j = 0; j < 4; ++j)
                    acc[i][j] = fmaf(qr[i], kr[j], acc[i][j]);
        }
    }
    #pragma unroll
    for (int i = 0; i < 4; ++i)
        #pragma unroll
        for (int j = 0; j < 4; ++j)
            atomicAdd(&A[(h * 64 + n0 + i) * 64 + m0 + j], acc[i][j]);
}

// ---------------------------------------------------------------------------
__global__ void softmax_kernel(const float* __restrict__ A, float* __restrict__ softA)
{
    const int row  = blockIdx.x;       // 0..511
    const int lane = threadIdx.x;      // 0..63
    const float inv_scale = (float)(1.0 / 362.03867196751236); // 1/sqrt(131072)
    float v = A[row * 64 + lane] * inv_scale;
    float mx = v;
    #pragma unroll
    for (int o = 32; o > 0; o >>= 1) mx = fmaxf(mx, __shfl_xor(mx, o, 64));
    float e = expf(v - mx);
    float s = e;
    #pragma unroll
    for (int o = 32; o > 0; o >>= 1) s += __shfl_xor(s, o, 64);
    softA[row * 64 + lane] = e / s;
}

// ---------------------------------------------------------------------------
__launch_bounds__(256)
__global__ void sa_kernel(const unsigned short* __restrict__ v_buf,
                          const float* __restrict__ softA,
                          unsigned short* __restrict__ sa_buf)
{
    __shared__ float sA[64 * 64];
    __shared__ float v_s[64 * 128];
    const int t = threadIdx.x;
    const int b = blockIdx.x;
    const int k     = b >> 6;      // 0..127
    const int chunk = b & 63;
    const int p0 = chunk * 128;
    const int h  = k >> 4;

    for (int idx = t; idx < 4096; idx += 256) sA[idx] = softA[h * 4096 + idx];
    for (int v8 = t; v8 < 1024; v8 += 256) {
        int m = v8 >> 4, pp = v8 & 15;
        uint4 vv = *reinterpret_cast<const uint4*>(v_buf + (size_t)(m * 128 + k) * HW + p0 + pp * 8);
        const unsigned short* u = reinterpret_cast<const unsigned short*>(&vv);
        #pragma unroll
        for (int j = 0; j < 8; ++j) v_s[m * 128 + pp * 8 + j] = b2f(u[j]);
    }
    __syncthreads();

    const int p  = t & 63;
    const int n0 = (t >> 6) * 16;
    float acc[16][2];
    #pragma unroll
    for (int i = 0; i < 16; ++i) { acc[i][0] = 0.f; acc[i][1] = 0.f; }
    for (int m = 0; m < 64; ++m) {
        float v0 = v_s[m * 128 + p];
        float v1 = v_s[m * 128 + p + 64];
        #pragma unroll
        for (int i = 0; i < 16; ++i) {
            float a = sA[(n0 + i) * 64 + m];
            acc[i][0] = fmaf(a, v0, acc[i][0]);
            acc[i][1] = fmaf(a, v1, acc[i][1]);
        }
    }
    #pragma unroll
    for (int i = 0; i < 16; ++i) {
        size_t base = (size_t)((n0 + i) * 128 + k) * HW + p0;
        sa_buf[base + p]      = f2b(acc[i][0]);
        sa_buf[base + p + 64] = f2b(acc[i][1]);
    }
}

// ---------------------------------------------------------------------------
__launch_bounds__(256)
__global__ void out_kernel(const unsigned short* __restrict__ sa_buf,
                           const float* __restrict__ Wout,
                           const float* __restrict__ bout,
                           float* __restrict__ out)
{
    __shared__ __align__(16) unsigned short sa_s[128 * 128];
    __shared__ float w_s[128 * 64];
    const int t = threadIdx.x;
    const int b = blockIdx.x;
    const int n     = b >> 6;
    const int chunk = b & 63;
    const int p0 = chunk * 128;

    for (int idx = t; idx < 8192; idx += 256) w_s[idx] = Wout[idx];
    for (int v8 = t; v8 < 2048; v8 += 256) {
        int k = v8 >> 4, pp = v8 & 15;
        uint4 vv = *reinterpret_cast<const uint4*>(sa_buf + (size_t)(n * 128 + k) * HW + p0 + pp * 8);
        *reinterpret_cast<uint4*>(&sa_s[k * 128 + pp * 8]) = vv;
    }
    __syncthreads();

    const int p  = t & 63;
    const int d0 = (t >> 6) * 16;
    float acc[16][2];
    #pragma unroll
    for (int i = 0; i < 16; ++i) { acc[i][0] = 0.f; acc[i][1] = 0.f; }
    for (int k = 0; k < 128; ++k) {
        float s0 = b2f(sa_s[k * 128 + p]);
        float s1 = b2f(sa_s[k * 128 + p + 64]);
        #pragma unroll
        for (int i = 0; i < 16; ++i) {
            float w = w_s[k * 64 + d0 + i];
            acc[i][0] = fmaf(s0, w, acc[i][0]);
            acc[i][1] = fmaf(s1, w, acc[i][1]);
        }
    }
    #pragma unroll
    for (int i = 0; i < 16; ++i) {
        float bb = bout[d0 + i];
        size_t base = (size_t)(n * 64 + d0 + i) * HW + p0;
        out[base + p]      = acc[i][0] + bb;
        out[base + p + 64] = acc[i][1] + bb;
    }
}

// ---------------------------------------------------------------------------
extern "C" void kernel_launch(void* const* d_in, const int* in_sizes, int n_in,
                              void* d_out, int out_size, void* d_ws, size_t ws_size,
                              hipStream_t stream)
{
    const float* x    = (const float*)d_in[0];
    const float* Wqk  = (const float*)d_in[1];
    const float* bqk  = (const float*)d_in[2];
    const float* Wv   = (const float*)d_in[3];
    const float* bv   = (const float*)d_in[4];
    const float* Wout = (const float*)d_in[5];
    const float* bout = (const float*)d_in[6];
    float* out = (float*)d_out;

    char* ws = (char*)d_ws;
    // layout: qk_buf bf16 [64][256][8192] (268435456 B)  -- reused as sa_buf
    //         v_buf  bf16 [64][128][8192] (134217728 B)
    //         A      f32  [8][64][64]     (131072 B)
    //         softA  f32  [8][64][64]     (131072 B)
    //         Wb     bf16 [9][384][64]    (442368 B)
    unsigned short* qk_buf = (unsigned short*)ws;
    unsigned short* v_buf  = (unsigned short*)(ws + 268435456u);
    float* A     = (float*)(ws + 268435456u + 134217728u);
    float* softA = (float*)(ws + 268435456u + 134217728u + 131072u);
    unsigned short* Wb = (unsigned short*)(ws + 268435456u + 134217728u + 131072u + 131072u);
    unsigned short* sa_buf = qk_buf;   // overlays dead q/k after A computed

    hipMemsetAsync(A, 0, 131072, stream);
    cast_w_kernel<<<384, 256, 0, stream>>>(Wqk, Wv, Wb);
    conv_mfma_kernel<<<dim3(3, 32, 64), 512, 0, stream>>>(x, Wb, bqk, bv, qk_buf, v_buf);
    a_kernel<<<dim3(32, 8), 256, 0, stream>>>(qk_buf, A);
    softmax_kernel<<<512, 64, 0, stream>>>(A, softA);
    sa_kernel<<<8192, 256, 0, stream>>>(v_buf, softA, sa_buf);
    out_kernel<<<4096, 256, 0, stream>>>(sa_buf, Wout, bout, out);
}

// Round 3
// 679.186 us; speedup vs baseline: 6.0611x; 2.0603x over previous
//
#include <hip/hip_runtime.h>
#include <hip/hip_bf16.h>
#include <stdint.h>

#define HW 8192
typedef short short8 __attribute__((ext_vector_type(8)));
typedef float f32x4 __attribute__((ext_vector_type(4)));

__device__ __forceinline__ float b2f(unsigned short u) {
    union { unsigned int i; float f; } x; x.i = ((unsigned int)u) << 16; return x.f;
}
__device__ __forceinline__ unsigned short f2b(float f) {
    union { float f; unsigned int i; } x; x.f = f;
    unsigned int lsb = (x.i >> 16) & 1u;
    x.i += 0x7fffu + lsb;
    return (unsigned short)(x.i >> 16);
}
__device__ __forceinline__ float blo(unsigned int u){ union{unsigned int i; float f;}x; x.i = u<<16; return x.f; }
__device__ __forceinline__ float bhi(unsigned int u){ union{unsigned int i; float f;}x; x.i = u & 0xffff0000u; return x.f; }

// ---------------------------------------------------------------------------
// Wb[tap][co][ci] bf16, co 0..383 (qk then v).  W global: [co][ci][3][3] f32.
// ---------------------------------------------------------------------------
__global__ void cast_w_kernel(const float* __restrict__ Wqk,
                              const float* __restrict__ Wv,
                              unsigned short* __restrict__ Wb)
{
    const int co = blockIdx.x;            // 0..383
    const int t  = threadIdx.x;
    const float* src = (co < 256) ? (Wqk + (size_t)co * 576)
                                  : (Wv + (size_t)(co - 256) * 576);
    for (int idx = t; idx < 576; idx += 256) {
        const int ci  = idx / 9;
        const int tap = idx - ci * 9;
        Wb[(size_t)tap * (384 * 64) + co * 64 + ci] = f2b(src[idx]);
    }
}

// ---------------------------------------------------------------------------
// x f32 NCHW -> xb bf16 NHWC ([n][pix][ci]), transposed through LDS.
// ---------------------------------------------------------------------------
__launch_bounds__(256)
__global__ void cast_x_kernel(const float* __restrict__ x,
                              unsigned short* __restrict__ xb)
{
    __shared__ __align__(16) unsigned short xt[256 * 64];   // [p][ci] swizzled
    const int t  = threadIdx.x;
    const int pc = blockIdx.x;   // 0..31
    const int n  = blockIdx.y;
    const size_t p0 = (size_t)pc * 256;

    const int ci0 = (t >> 6) * 16;
    const int pl  = (t & 63) * 4;
    unsigned short tmp[16][4];
    #pragma unroll
    for (int i = 0; i < 16; ++i) {
        const float4 v = *reinterpret_cast<const float4*>(
            x + ((size_t)n * 64 + ci0 + i) * HW + p0 + pl);
        tmp[i][0] = f2b(v.x); tmp[i][1] = f2b(v.y);
        tmp[i][2] = f2b(v.z); tmp[i][3] = f2b(v.w);
    }
    #pragma unroll
    for (int p = 0; p < 4; ++p) {
        const int pp = pl + p;
        #pragma unroll
        for (int half = 0; half < 2; ++half) {
            short8 v;
            #pragma unroll
            for (int j = 0; j < 8; ++j) v[j] = (short)tmp[half * 8 + j][p];
            const int gx = (ci0 >> 3) + half;
            *reinterpret_cast<short8*>(&xt[pp * 64 + ((gx ^ (pp & 7)) << 3)]) = v;
        }
    }
    __syncthreads();
    #pragma unroll
    for (int i = 0; i < 8; ++i) {
        const int id = t + i * 256;
        const int pp = id >> 3, gx = id & 7;
        const uint4 v = *reinterpret_cast<const uint4*>(
            &xt[pp * 64 + ((gx ^ (pp & 7)) << 3)]);
        *reinterpret_cast<uint4*>(
            &xb[((size_t)n * HW + p0 + pp) * 64 + gx * 8]) = v;
    }
}

// ---------------------------------------------------------------------------
// Implicit-GEMM conv, MFMA 16x16x32 bf16.
// Block: 512 thr (8 waves), pixel tile 8x32, co-loop over 3 cb (128 co each).
// x halo (10x34 pos x 64ci) staged once, swizzled.  W single-buffered per tap
// (K=64), reg-prefetched across the barrier.  LDS-transpose epilogue.
// ---------------------------------------------------------------------------
__launch_bounds__(512, 4)
__global__ void conv_mfma_kernel(const unsigned short* __restrict__ xb,
                                 const unsigned short* __restrict__ Wb,
                                 const float* __restrict__ bqk,
                                 const float* __restrict__ bv,
                                 unsigned short* __restrict__ qk_buf,
                                 unsigned short* __restrict__ v_buf)
{
    __shared__ __align__(16) unsigned short x_s[340 * 64];   // 43520 B
    __shared__ __align__(16) unsigned short w_s[128 * 64];   // 16384 B (reused as epilogue buf)
    __shared__ float bias_s[384];

    const int t   = threadIdx.x;
    const int bid = blockIdx.x;
    const int wg  = (bid & 7) * 256 + (bid >> 3);   // XCD swizzle (2048 % 8 == 0)
    const int tile = wg & 31;
    const int n    = wg >> 5;
    const int i0 = (tile >> 2) * 8;
    const int j0 = (tile & 3) * 32;

    if (t < 384) bias_s[t] = (t < 256) ? bqk[t] : bv[t - 384 + 128];
    // (t in [256,384) -> bv[t-256])
    if (t >= 256 && t < 384) bias_s[t] = bv[t - 256];

    // ---- stage x halo: 340 positions x 8 granules ----
    for (int id = t; id < 340 * 8; id += 512) {
        const int pos = id >> 3, g = id & 7;
        const int r = pos / 34, c = pos - r * 34;
        const int gi = i0 - 1 + r, gj = j0 - 1 + c;
        uint4 v = {0u, 0u, 0u, 0u};
        if ((unsigned)gi < 64u && (unsigned)gj < 128u)
            v = *reinterpret_cast<const uint4*>(
                &xb[((size_t)n * HW + gi * 128 + gj) * 64 + g * 8]);
        *reinterpret_cast<uint4*>(&x_s[pos * 64 + ((g ^ (pos & 7)) << 3)]) = v;
    }

    // ---- W staging roles ----
    const int wco = t >> 3;        // 0..63 (plus +64 for 2nd task)
    const int wgw = t & 7;
    const int wdst0 = wco * 64 + ((wgw ^ (wco & 7)) << 3);
    const int wdst1 = (wco + 64) * 64 + ((wgw ^ ((wco + 64) & 7)) << 3);

    // stage W for step 0 (cb0, tap0)
    *reinterpret_cast<uint4*>(&w_s[wdst0]) =
        *reinterpret_cast<const uint4*>(&Wb[(size_t)wco * 64 + wgw * 8]);
    *reinterpret_cast<uint4*>(&w_s[wdst1]) =
        *reinterpret_cast<const uint4*>(&Wb[(size_t)(wco + 64) * 64 + wgw * 8]);
    __syncthreads();

    // ---- wave decomposition ----
    const int lane15 = t & 15;
    const int lg     = (t >> 4) & 3;
    const int wid    = t >> 6;
    const int wco0   = (wid >> 2) * 64;
    const int pq     = wid & 3;

    f32x4 acc[4][4];
    #pragma unroll
    for (int m = 0; m < 4; ++m)
        #pragma unroll
        for (int r = 0; r < 4; ++r) acc[m][r] = (f32x4){0.f, 0.f, 0.f, 0.f};

    int cb = 0, tap = 0;
    for (int s = 0; s < 27; ++s) {
        // prefetch next step's W
        uint4 wpre0, wpre1;
        if (s < 26) {
            int tap2 = tap + 1, cb2 = cb;
            if (tap2 == 9) { tap2 = 0; cb2 = cb + 1; }
            const unsigned short* wsrc = Wb + ((size_t)tap2 * 384 + cb2 * 128) * 64;
            wpre0 = *reinterpret_cast<const uint4*>(wsrc + wco * 64 + wgw * 8);
            wpre1 = *reinterpret_cast<const uint4*>(wsrc + (wco + 64) * 64 + wgw * 8);
        }
        const int di = (tap * 11) >> 5;      // tap/3
        const int dj = tap - di * 3;

        #pragma unroll
        for (int kc = 0; kc < 2; ++kc) {
            short8 af[4], bf[4];
            #pragma unroll
            for (int m = 0; m < 4; ++m) {
                const int co_l = wco0 + m * 16 + lane15;
                af[m] = *reinterpret_cast<const short8*>(
                    &w_s[co_l * 64 + (((kc * 4 + lg) ^ (co_l & 7)) << 3)]);
            }
            #pragma unroll
            for (int r = 0; r < 4; ++r) {
                const int pos = (pq * 2 + (r >> 1) + di) * 34 + (r & 1) * 16 + lane15 + dj;
                bf[r] = *reinterpret_cast<const short8*>(
                    &x_s[pos * 64 + (((kc * 4 + lg) ^ (pos & 7)) << 3)]);
            }
            #pragma unroll
            for (int m = 0; m < 4; ++m)
                #pragma unroll
                for (int r = 0; r < 4; ++r)
                    acc[m][r] = __builtin_amdgcn_mfma_f32_16x16x32_bf16(
                        af[m], bf[r], acc[m][r], 0, 0, 0);
        }

        if (tap == 8) {
            // ---- epilogue for this cb: transpose through w_s, 64B stores ----
            const bool is_v = (cb == 2);
            #pragma unroll
            for (int p4 = 0; p4 < 4; ++p4) {
                __syncthreads();
                const int hb = p4 >> 1, mp = (p4 & 1) * 2;
                if ((wid >> 2) == hb) {
                    #pragma unroll
                    for (int mi = 0; mi < 2; ++mi) {
                        #pragma unroll
                        for (int r = 0; r < 4; ++r) {
                            const int pix = (pq * 2 + (r >> 1)) * 32 + (r & 1) * 16 + lane15;
                            #pragma unroll
                            for (int reg = 0; reg < 4; ++reg) {
                                const int cw = mi * 16 + lg * 4 + reg;
                                const int co_tile = hb * 64 + mp * 16 + cw;
                                float v;
                                if (p4 == 0)      v = acc[0 + mi][r][reg];
                                else if (p4 == 1) v = acc[2 + mi][r][reg];
                                else if (p4 == 2) v = acc[0 + mi][r][reg];
                                else              v = acc[2 + mi][r][reg];
                                w_s[cw * 256 + pix] = f2b(v + bias_s[cb * 128 + co_tile]);
                            }
                        }
                    }
                }
                __syncthreads();
                #pragma unroll
                for (int i = 0; i < 2; ++i) {
                    const int e = t * 2 + i;
                    const int co_w = e >> 5, ch = e & 31;
                    const int pix0 = ch * 8;
                    const uint4 v = *reinterpret_cast<const uint4*>(&w_s[co_w * 256 + pix0]);
                    const int co_tile = p4 * 32 + co_w;
                    const int row = pix0 >> 5, cc = pix0 & 31;
                    unsigned short* dst = is_v
                        ? (v_buf + ((size_t)n * 128 + co_tile) * HW)
                        : (qk_buf + ((size_t)n * 256 + cb * 128 + co_tile) * HW);
                    *reinterpret_cast<uint4*>(&dst[(i0 + row) * 128 + j0 + cc]) = v;
                }
            }
            #pragma unroll
            for (int m = 0; m < 4; ++m)
                #pragma unroll
                for (int r = 0; r < 4; ++r) acc[m][r] = (f32x4){0.f, 0.f, 0.f, 0.f};
            cb += 1; tap = 0;
        } else {
            tap += 1;
        }

        if (s < 26) {
            __syncthreads();
            *reinterpret_cast<uint4*>(&w_s[wdst0]) = wpre0;
            *reinterpret_cast<uint4*>(&w_s[wdst1]) = wpre1;
            __syncthreads();
        }
    }
}

// ---------------------------------------------------------------------------
// A[h][n][m] = sum_{c,p} q.k via MFMA; split-K over 64 pixel chunks; atomicAdd.
// ---------------------------------------------------------------------------
__launch_bounds__(256)
__global__ void a_mfma_kernel(const unsigned short* __restrict__ qk_buf,
                              float* __restrict__ A)
{
    __shared__ __align__(16) unsigned short q_s[64 * 128];
    __shared__ __align__(16) unsigned short k_s[64 * 128];
    const int t  = threadIdx.x;
    const int pc = blockIdx.x;   // 0..63
    const int h  = blockIdx.y;   // 0..7
    const int p0 = pc * 128;
    const int lane15 = t & 15, lg = (t >> 4) & 3, wid = t >> 6;
    const int nh = wid >> 1, mh = wid & 1;

    f32x4 acc[2][2];
    #pragma unroll
    for (int a = 0; a < 2; ++a)
        #pragma unroll
        for (int b = 0; b < 2; ++b) acc[a][b] = (f32x4){0.f, 0.f, 0.f, 0.f};

    for (int c = 0; c < 16; ++c) {
        __syncthreads();
        for (int id = t; id < 2048; id += 256) {
            const int arr = id >> 10, rem = id & 1023;
            const int nn = rem >> 4, g = rem & 15;
            const int ch = h * 32 + arr * 16 + c;
            const uint4 v = *reinterpret_cast<const uint4*>(
                &qk_buf[((size_t)nn * 256 + ch) * HW + p0 + g * 8]);
            unsigned short* dstbuf = arr ? k_s : q_s;
            *reinterpret_cast<uint4*>(&dstbuf[nn * 128 + ((g ^ (nn & 15)) << 3)]) = v;
        }
        __syncthreads();
        #pragma unroll
        for (int kk = 0; kk < 4; ++kk) {
            short8 aq[2], bk[2];
            #pragma unroll
            for (int ai = 0; ai < 2; ++ai) {
                const int nl = nh * 32 + ai * 16 + lane15;
                aq[ai] = *reinterpret_cast<const short8*>(
                    &q_s[nl * 128 + (((kk * 4 + lg) ^ (nl & 15)) << 3)]);
            }
            #pragma unroll
            for (int bj = 0; bj < 2; ++bj) {
                const int ml = mh * 32 + bj * 16 + lane15;
                bk[bj] = *reinterpret_cast<const short8*>(
                    &k_s[ml * 128 + (((kk * 4 + lg) ^ (ml & 15)) << 3)]);
            }
            #pragma unroll
            for (int ai = 0; ai < 2; ++ai)
                #pragma unroll
                for (int bj = 0; bj < 2; ++bj)
                    acc[ai][bj] = __builtin_amdgcn_mfma_f32_16x16x32_bf16(
                        aq[ai], bk[bj], acc[ai][bj], 0, 0, 0);
        }
    }
    #pragma unroll
    for (int ai = 0; ai < 2; ++ai)
        #pragma unroll
        for (int bj = 0; bj < 2; ++bj)
            #pragma unroll
            for (int reg = 0; reg < 4; ++reg) {
                const int nn = nh * 32 + ai * 16 + lg * 4 + reg;
                const int mm = mh * 32 + bj * 16 + lane15;
                atomicAdd(&A[(h * 64 + nn) * 64 + mm], acc[ai][bj][reg]);
            }
}

// ---------------------------------------------------------------------------
__global__ void softmax_kernel(const float* __restrict__ A, float* __restrict__ softA)
{
    const int row  = blockIdx.x;       // 0..511
    const int lane = threadIdx.x;      // 0..63
    const float inv_scale = (float)(1.0 / 362.03867196751236); // 1/sqrt(131072)
    float v = A[row * 64 + lane] * inv_scale;
    float mx = v;
    #pragma unroll
    for (int o = 32; o > 0; o >>= 1) mx = fmaxf(mx, __shfl_xor(mx, o, 64));
    float e = expf(v - mx);
    float s = e;
    #pragma unroll
    for (int o = 32; o > 0; o >>= 1) s += __shfl_xor(s, o, 64);
    softA[row * 64 + lane] = e / s;
}

// ---------------------------------------------------------------------------
// sa[n][k][p] = sum_m softA[h(k)][n][m] * v[m][k][p]; bf16 out.
// Block (pc, k): 512 thr, thread tile 8n x 4p.
// ---------------------------------------------------------------------------
__launch_bounds__(512)
__global__ void sa_kernel2(const unsigned short* __restrict__ v_buf,
                           const float* __restrict__ softA,
                           unsigned short* __restrict__ sa_buf)
{
    __shared__ float sA[4096];                              // 16 KB
    __shared__ __align__(16) unsigned short v_s[64 * 256];  // 32 KB
    const int t  = threadIdx.x;
    const int pc = blockIdx.x;   // 0..31
    const int k  = blockIdx.y;   // 0..127
    const int p0 = pc * 256;
    const int h  = k >> 4;

    for (int id = t; id < 4096; id += 512) sA[id] = softA[h * 4096 + id];
    #pragma unroll
    for (int i = 0; i < 4; ++i) {
        const int id = t + i * 512;
        const int m = id >> 5, g = id & 31;
        *reinterpret_cast<uint4*>(&v_s[m * 256 + g * 8]) =
            *reinterpret_cast<const uint4*>(
                &v_buf[((size_t)m * 128 + k) * HW + p0 + g * 8]);
    }
    __syncthreads();

    const int pg = t & 63, ng = t >> 6;
    const int n0 = ng * 8, pp = pg * 4;
    float acc[8][4];
    #pragma unroll
    for (int i = 0; i < 8; ++i)
        #pragma unroll
        for (int j = 0; j < 4; ++j) acc[i][j] = 0.f;

    for (int m = 0; m < 64; ++m) {
        const uint2 vv = *reinterpret_cast<const uint2*>(&v_s[m * 256 + pp]);
        const float v0 = blo(vv.x), v1 = bhi(vv.x), v2 = blo(vv.y), v3 = bhi(vv.y);
        #pragma unroll
        for (int i = 0; i < 8; ++i) {
            const float a = sA[(n0 + i) * 64 + m];
            acc[i][0] = fmaf(a, v0, acc[i][0]);
            acc[i][1] = fmaf(a, v1, acc[i][1]);
            acc[i][2] = fmaf(a, v2, acc[i][2]);
            acc[i][3] = fmaf(a, v3, acc[i][3]);
        }
    }
    #pragma unroll
    for (int i = 0; i < 8; ++i) {
        uint2 o;
        o.x = (unsigned)f2b(acc[i][0]) | ((unsigned)f2b(acc[i][1]) << 16);
        o.y = (unsigned)f2b(acc[i][2]) | ((unsigned)f2b(acc[i][3]) << 16);
        *reinterpret_cast<uint2*>(
            &sa_buf[((size_t)(n0 + i) * 128 + k) * HW + p0 + pp]) = o;
    }
}

// ---------------------------------------------------------------------------
// out[n][d][p] = sum_k sa[n][k][p] * Wout[k][d] + bout[d]; f32 out.
// Block (pc, n): 256 thr, thread tile 8d x 4p.  Wout cast to bf16 in LDS.
// ---------------------------------------------------------------------------
__launch_bounds__(256)
__global__ void out_kernel2(const unsigned short* __restrict__ sa_buf,
                            const float* __restrict__ Wout,
                            const float* __restrict__ bout,
                            float* __restrict__ out)
{
    __shared__ __align__(16) unsigned short w_s[128 * 64];     // 16 KB bf16
    __shared__ __align__(16) unsigned short sa_s[128 * 128];   // 32 KB
    const int t  = threadIdx.x;
    const int pc = blockIdx.x;   // 0..63
    const int n  = blockIdx.y;   // 0..63
    const int p0 = pc * 128;

    #pragma unroll
    for (int i = 0; i < 8; ++i) {
        const int id = t + i * 256;          // 2048 quads of 4 f32
        const float4 wv = *reinterpret_cast<const float4*>(&Wout[id * 4]);
        uint2 o;
        o.x = (unsigned)f2b(wv.x) | ((unsigned)f2b(wv.y) << 16);
        o.y = (unsigned)f2b(wv.z) | ((unsigned)f2b(wv.w) << 16);
        *reinterpret_cast<uint2*>(&w_s[id * 4]) = o;
    }
    #pragma unroll
    for (int i = 0; i < 8; ++i) {
        const int id = t + i * 256;
        const int kk = id >> 4, g = id & 15;
        *reinterpret_cast<uint4*>(&sa_s[kk * 128 + g * 8]) =
            *reinterpret_cast<const uint4*>(
                &sa_buf[((size_t)n * 128 + kk) * HW + p0 + g * 8]);
    }
    __syncthreads();

    const int pg = t & 31, dg = t >> 5;
    const int pp = pg * 4, d0 = dg * 8;
    float acc[8][4];
    #pragma unroll
    for (int i = 0; i < 8; ++i)
        #pragma unroll
        for (int j = 0; j < 4; ++j) acc[i][j] = 0.f;

    for (int k = 0; k < 128; ++k) {
        const uint2 sv = *reinterpret_cast<const uint2*>(&sa_s[k * 128 + pp]);
        const float s0 = blo(sv.x), s1 = bhi(sv.x), s2 = blo(sv.y), s3 = bhi(sv.y);
        const uint4 wv = *reinterpret_cast<const uint4*>(&w_s[k * 64 + d0]);
        const float w0 = blo(wv.x), w1 = bhi(wv.x), w2 = blo(wv.y), w3 = bhi(wv.y);
        const float w4 = blo(wv.z), w5 = bhi(wv.z), w6 = blo(wv.w), w7 = bhi(wv.w);
        const float wr[8] = {w0, w1, w2, w3, w4, w5, w6, w7};
        #pragma unroll
        for (int i = 0; i < 8; ++i) {
            acc[i][0] = fmaf(s0, wr[i], acc[i][0]);
            acc[i][1] = fmaf(s1, wr[i], acc[i][1]);
            acc[i][2] = fmaf(s2, wr[i], acc[i][2]);
            acc[i][3] = fmaf(s3, wr[i], acc[i][3]);
        }
    }
    #pragma unroll
    for (int i = 0; i < 8; ++i) {
        const float bb = bout[d0 + i];
        float4 o;
        o.x = acc[i][0] + bb; o.y = acc[i][1] + bb;
        o.z = acc[i][2] + bb; o.w = acc[i][3] + bb;
        *reinterpret_cast<float4*>(
            &out[((size_t)n * 64 + d0 + i) * HW + p0 + pp]) = o;
    }
}

// ---------------------------------------------------------------------------
extern "C" void kernel_launch(void* const* d_in, const int* in_sizes, int n_in,
                              void* d_out, int out_size, void* d_ws, size_t ws_size,
                              hipStream_t stream)
{
    const float* x    = (const float*)d_in[0];
    const float* Wqk  = (const float*)d_in[1];
    const float* bqk  = (const float*)d_in[2];
    const float* Wv   = (const float*)d_in[3];
    const float* bv   = (const float*)d_in[4];
    const float* Wout = (const float*)d_in[5];
    const float* bout = (const float*)d_in[6];
    float* out = (float*)d_out;

    char* ws = (char*)d_ws;
    // ws layout (same as R2): qk_buf bf16 [64][256][8192] (268435456 B, reused as sa_buf)
    //   v_buf bf16 [64][128][8192] (134217728) | A f32 (131072) | softA f32 (131072)
    //   Wb bf16 [9][384][64] (442368)
    unsigned short* qk_buf = (unsigned short*)ws;
    unsigned short* v_buf  = (unsigned short*)(ws + 268435456u);
    float* A     = (float*)(ws + 268435456u + 134217728u);
    float* softA = (float*)(ws + 268435456u + 134217728u + 131072u);
    unsigned short* Wb = (unsigned short*)(ws + 268435456u + 134217728u + 262144u);
    unsigned short* sa_buf = qk_buf;            // overlays dead q/k after A
    unsigned short* xb = (unsigned short*)d_out; // 67 MB scratch in d_out (dead until out_kernel2)

    hipMemsetAsync(A, 0, 131072, stream);
    cast_w_kernel<<<384, 256, 0, stream>>>(Wqk, Wv, Wb);
    cast_x_kernel<<<dim3(32, 64), 256, 0, stream>>>(x, xb);
    conv_mfma_kernel<<<2048, 512, 0, stream>>>(xb, Wb, bqk, bv, qk_buf, v_buf);
    a_mfma_kernel<<<dim3(64, 8), 256, 0, stream>>>(qk_buf, A);
    softmax_kernel<<<512, 64, 0, stream>>>(A, softA);
    sa_kernel2<<<dim3(32, 128), 512, 0, stream>>>(v_buf, softA, sa_buf);
    out_kernel2<<<dim3(64, 64), 256, 0, stream>>>(sa_buf, Wout, bout, out);
}